// Round 17
// baseline (611.894 us; speedup 1.0000x reference)
//
#include <hip/hip_runtime.h>
#include <hip/hip_fp8.h>
#include <math.h>

#define NN 20000
#define NPAD 20096          // 157*128 padded rows
#define NE 640000
#define NOUT 1152           // GEMM cols: Q(256)|K(256)|V(256)|SKIP(256)|qe(8)|qb(1)|pad
#define GSS 272             // gsk row stride f16: skip[0..255] qe[256..263] qb[264] pad
#define KVB 512             // kvt row bytes: k i8[256] | v fp8[256]
#define CAP 80              // bucket capacity per node (validated R8..R16)
#define RECB 32             // edge record: ea f16x8 @0 | src i32 @16 | w f32 @20 | pad
#define SCQ 0.09016994f     // (1/sqrt(256)) * log2(e)
#define ISCL 8.8057e-5f     // SCQ / 1024  (int8 q,k both at scale 32)
// fragment-tiled index: [rowtile16][kblk8][r16][k8]
#define TIDX(r,k) ((((r)>>4)*4096) + (((k)>>3)*128) + (((r)&15)*8) + ((k)&7))

typedef _Float16 f16;
typedef f16 f16x8 __attribute__((ext_vector_type(8)));
typedef f16 f16x4 __attribute__((ext_vector_type(4)));
typedef f16 h2    __attribute__((ext_vector_type(2)));
typedef float f32x4 __attribute__((ext_vector_type(4)));
typedef float f32x2 __attribute__((ext_vector_type(2)));

static __device__ __forceinline__ float fdot2(h2 a, h2 b, float c) {
#if __has_builtin(__builtin_amdgcn_fdot2)
  return __builtin_amdgcn_fdot2(a, b, c, false);
#else
  return c + (float)a[0]*(float)b[0] + (float)a[1]*(float)b[1];
#endif
}

static __device__ __forceinline__ float fast_exp2(float x) {
#if __has_builtin(__builtin_amdgcn_exp2f)
  return __builtin_amdgcn_exp2f(x);
#else
  return exp2f(x);
#endif
}

static __device__ __forceinline__ int sdot4(unsigned a, unsigned b, int c) {
#if __has_builtin(__builtin_amdgcn_sdot4)
  return __builtin_amdgcn_sdot4((int)a, (int)b, c, false);
#else
  int r = c;
  #pragma unroll
  for (int i = 0; i < 4; i++) {
    int ai = ((int)((a >> (8*i)) & 255) ^ 128) - 128;
    int bi = ((int)((b >> (8*i)) & 255) ^ 128) - 128;
    r += ai*bi;
  }
  return r;
#endif
}

static __device__ __forceinline__ unsigned pack_i8x4(float a, float b, float c, float d) {
  int i0 = (int)rintf(a), i1 = (int)rintf(b), i2 = (int)rintf(c), i3 = (int)rintf(d);
  i0 = max(-127, min(127, i0)); i1 = max(-127, min(127, i1));
  i2 = max(-127, min(127, i2)); i3 = max(-127, min(127, i3));
  return (unsigned)(i0 & 255) | ((unsigned)(i1 & 255) << 8)
       | ((unsigned)(i2 & 255) << 16) | ((unsigned)(i3 & 255) << 24);
}

static __device__ __forceinline__ unsigned pack_fp8x4(float a, float b, float c, float d) {
#if __has_builtin(__builtin_amdgcn_cvt_pk_fp8_f32)
  int r = __builtin_amdgcn_cvt_pk_fp8_f32(a, b, 0, false);
  r = __builtin_amdgcn_cvt_pk_fp8_f32(c, d, r, true);
  return (unsigned)r;
#else
  __hip_fp8_e4m3 w(a), x2(b), y(c), z(d);
  return (unsigned)w.__x | ((unsigned)x2.__x<<8) | ((unsigned)y.__x<<16) | ((unsigned)z.__x<<24);
#endif
}

template<bool HI>
static __device__ __forceinline__ f32x2 unpack_fp8x2(unsigned v) {
#if __has_builtin(__builtin_amdgcn_cvt_pk_f32_fp8)
  return __builtin_amdgcn_cvt_pk_f32_fp8((int)v, HI);
#else
  unsigned s = HI ? (v >> 16) : (v & 0xffff);
  __hip_fp8_e4m3 a, b; a.__x = (unsigned char)(s & 0xff); b.__x = (unsigned char)(s >> 8);
  return (f32x2){ (float)a, (float)b };
#endif
}

// ---------------- merged weight prep + pad-zero ----------------
// blocks 0..46: Wcomb | 47..366: tr | 367..411: extra | 412..416: bt | 417/418: h pads
__global__ __launch_bounds__(256) void k_prep_all(
    const float* __restrict__ W_emb, const float* __restrict__ W_t,
    const float* __restrict__ W_s,   const float* __restrict__ W_f,
    const float* __restrict__ b_emb, const float* __restrict__ b_t,
    const float* __restrict__ b_s,   const float* __restrict__ b_f,
    const float* __restrict__ Wq, const float* __restrict__ Wk,
    const float* __restrict__ Wv, const float* __restrict__ Wsk,
    const float* __restrict__ We, const float* __restrict__ be,
    const float* __restrict__ bq, const float* __restrict__ bk,
    const float* __restrict__ bv, const float* __restrict__ bsk,
    f16* __restrict__ Wch, float* __restrict__ bc,
    f16* __restrict__ WT, float* __restrict__ b_all,
    f16* __restrict__ hA, f16* __restrict__ hB)
{
  __shared__ float smem[64*65];
  int b = blockIdx.x;
  int tid = threadIdx.x;

  if (b < 47) {                        // ---- Wcomb ----
    int r = b, c = tid;
    if (r < 36) {
      float a = 0.f;
      for (int m = 0; m < 256; m++) a += W_emb[r*256+m] * W_f[m*256+c];
      Wch[r*256+c] = (f16)a;
    } else if (r < 40) {
      int rr = r - 36; float a = 0.f;
      for (int m = 0; m < 256; m++) a += W_t[rr*256+m] * W_f[(256+m)*256+c];
      Wch[r*256+c] = (f16)a;
    } else if (r < 46) {
      int rr = r - 40; float a = 0.f;
      for (int m = 0; m < 256; m++) a += W_s[rr*256+m] * W_f[(512+m)*256+c];
      Wch[r*256+c] = (f16)a;
    } else {
      float a = b_f[c];
      for (int m = 0; m < 256; m++) a += b_emb[m]*W_f[m*256+c];
      for (int m = 0; m < 256; m++) a += b_t[m]*W_f[(256+m)*256+c];
      for (int m = 0; m < 256; m++) a += b_s[m]*W_f[(512+m)*256+c];
      bc[c] = a;
    }
  } else if (b < 367) {                // ---- tr: W[k][n] f32 -> WT tiled f16 ----
    float (*lds)[65] = (float(*)[65])smem;
    int bb = b - 47;
    int nt = bb & 3, kt = (bb >> 2) & 3, mat = (bb >> 4) & 3, L = bb >> 6;
    const float* src = (mat == 0 ? Wq : mat == 1 ? Wk : mat == 2 ? Wv : Wsk) + (size_t)L*65536;
    int k0 = kt*64, n0 = nt*64;
    int c = tid & 63, r4 = tid >> 6;
    #pragma unroll
    for (int rr = 0; rr < 16; rr++) {
      int row = rr*4 + r4;
      lds[row][c] = src[(size_t)(k0 + row)*256 + n0 + c];
    }
    __syncthreads();
    f16* dst = WT + (size_t)L*294912;
    int nl = tid & 63, kb2 = tid >> 6;
    int ng = mat*256 + n0 + nl;
    #pragma unroll
    for (int half = 0; half < 2; half++) {
      int kb = kb2 + half*4;
      f16x8 v;
      #pragma unroll
      for (int e = 0; e < 8; e++) v[e] = (f16)lds[kb*8 + e][nl];
      *(f16x8*)(dst + TIDX(ng, k0 + kb*8)) = v;
    }
  } else if (b < 412) {                // ---- extra: qe/qb cols of WT ----
    float* vec = smem;
    int bb = b - 367;
    int L = bb / 9;
    int t = bb % 9;
    vec[tid] = (t < 8) ? We[(size_t)L*2048 + t*256 + tid] : be[(size_t)L*256 + tid];
    __syncthreads();
    int wave = tid >> 6, lane = tid & 63;
    for (int k = wave; k < 256; k += 4) {
      f32x4 wq = *(const f32x4*)(Wq + (size_t)L*65536 + (size_t)k*256 + lane*4);
      f32x4 vv = *(const f32x4*)(vec + lane*4);
      float d = wq[0]*vv[0] + wq[1]*vv[1] + wq[2]*vv[2] + wq[3]*vv[3];
      #pragma unroll
      for (int o = 32; o; o >>= 1) d += __shfl_xor(d, o, 64);
      if (lane == 0) WT[(size_t)L*294912 + TIDX(1024 + t, k)] = (f16)d;
    }
  } else if (b < 417) {                // ---- bt: fused bias ----
    int L = b - 412;
    for (int c = tid; c < NOUT; c += 256) {
      float v;
      if (c < 256)       v = bq [L*256+c];
      else if (c < 512)  v = bk [L*256+(c-256)];
      else if (c < 768)  v = bv [L*256+(c-512)];
      else if (c < 1024) v = bsk[L*256+(c-768)];
      else if (c < 1032) {
        int t = c-1024; float a = 0.f;
        for (int m = 0; m < 256; m++) a += bq[L*256+m]*We[(size_t)L*2048 + t*256 + m];
        v = a;
      } else if (c == 1032) {
        float a = 0.f;
        for (int m = 0; m < 256; m++) a += bq[L*256+m]*be[L*256+m];
        v = a;
      } else v = 0.f;
      b_all[(size_t)L*NOUT + c] = v;
    }
  } else {                             // ---- zero pad rows [NN, NPAD) of hA/hB ----
    f16* p = (b == 417 ? hA : hB) + (size_t)NN*256;   // TIDX tail is contiguous
    f16x8 z = {};
    for (int i = tid; i < (NPAD-NN)*256/8; i += 256)
      *(f16x8*)(p + (size_t)i*8) = z;
  }
}

// ---------------- bucketized scatter: one 32B record per edge ----------------
__global__ void k_scatter(const int* __restrict__ ei, const float* __restrict__ eattr,
                          int* cnt, char* __restrict__ rec)
{
  int e = blockIdx.x*256 + threadIdx.x;
  if (e < NE) {
    int d = ei[NE + e];
    int pos = atomicAdd(&cnt[d], 1);
    char* rp = rec + (size_t)(d*CAP + pos)*RECB;
    f32x4 a0 = *(const f32x4*)(eattr + (size_t)e*8);
    f32x4 a1 = *(const f32x4*)(eattr + (size_t)e*8 + 4);
    f16x8 ea = { (f16)a0[0],(f16)a0[1],(f16)a0[2],(f16)a0[3],
                 (f16)a1[0],(f16)a1[1],(f16)a1[2],(f16)a1[3] };
    *(f16x8*)rp = ea;
    *(int*)(rp + 16) = ei[e];
  }
}

// ---------------- encoder: 16 nodes/block, Wc f16 in LDS, per-node 16-lane shfl LN ----------------
__global__ __launch_bounds__(256) void k_encoder(
    const float* __restrict__ x, const float* __restrict__ t, const float* __restrict__ s,
    const f16* __restrict__ Wch, const float* __restrict__ bc,
    const float* __restrict__ lng, const float* __restrict__ lnb,
    f16* __restrict__ h)
{
  __shared__ f16 Wcs[46*256];
  __shared__ float xin[16][48];
  __shared__ float bcs[256], lgs[256], lbs[256];
  int tid = threadIdx.x;
  int u0 = blockIdx.x * 16;
  for (int i = tid; i < 46*128; i += 256)
    ((unsigned int*)Wcs)[i] = ((const unsigned int*)Wch)[i];
  bcs[tid] = bc[tid]; lgs[tid] = lng[tid]; lbs[tid] = lnb[tid];
  for (int i = tid; i < 576; i += 256) xin[i/36][i%36] = x[(size_t)u0*36 + i];
  if (tid < 64) xin[tid>>2][36 + (tid&3)] = t[(size_t)u0*4 + tid];
  if (tid < 96) xin[tid/6][40 + tid%6] = s[(size_t)u0*6 + tid];
  __syncthreads();
  int node = tid >> 4, cg = tid & 15;
  int u = u0 + node;
  float acc[16];
  #pragma unroll
  for (int j = 0; j < 16; j++) acc[j] = bcs[cg*16+j];
  for (int r = 0; r < 46; r++) {
    float xv = xin[node][r];
    const h2* wr = (const h2*)(Wcs + r*256 + cg*16);
    #pragma unroll
    for (int j2 = 0; j2 < 8; j2++) {
      h2 w2 = wr[j2];
      acc[j2*2]   += xv * (float)w2[0];
      acc[j2*2+1] += xv * (float)w2[1];
    }
  }
  float sm = 0.f, sq = 0.f;
  #pragma unroll
  for (int j = 0; j < 16; j++) { sm += acc[j]; sq += acc[j]*acc[j]; }
  #pragma unroll
  for (int o = 1; o < 16; o <<= 1) { sm += __shfl_xor(sm, o, 64); sq += __shfl_xor(sq, o, 64); }
  float mu  = sm * (1.f/256.f);
  float var = sq * (1.f/256.f) - mu*mu;
  float rin = rsqrtf(var + 1e-5f);
  f16x8 o0, o1;
  #pragma unroll
  for (int j = 0; j < 8; j++) {
    int c = cg*16 + j;
    float v = (acc[j]-mu)*rin*lgs[c] + lbs[c];
    o0[j] = (f16)fmaxf(v, 0.f);
  }
  #pragma unroll
  for (int j = 0; j < 8; j++) {
    int c = cg*16 + 8 + j;
    float v = (acc[8+j]-mu)*rin*lgs[c] + lbs[c];
    o1[j] = (f16)fmaxf(v, 0.f);
  }
  *(f16x8*)(h + TIDX(u, cg*16))   = o0;
  *(f16x8*)(h + TIDX(u, cg*16+8)) = o1;
}

// ---------------- MFMA GEMM: 8 waves/block (4m x 2n), wave 32x64, 1-deep prefetch ----------------
__global__ __launch_bounds__(512) void k_gemm(
    const f16* __restrict__ A, const f16* __restrict__ BT,
    const float* __restrict__ bias,
    unsigned char* __restrict__ qt8, unsigned char* __restrict__ kvt,
    f16* __restrict__ gsk)
{
  const int NWG = (NPAD/128)*9;           // 1413
  const int Q = NWG >> 3, R = NWG & 7;    // 176, 5
  int bid = blockIdx.x;
  int xcd = bid & 7, jj = bid >> 3;
  int wg = (xcd < R ? xcd*(Q+1) : R*(Q+1) + (xcd-R)*Q) + jj;
  int bmt = wg / 9, bnt = wg - bmt*9;

  int tid = threadIdx.x;
  int wave = tid >> 6, lane = tid & 63;
  int wm = wave >> 1, wn = wave & 1;        // 4m x 2n
  int rowbase = bmt*128 + wm*32;
  int colbase = bnt*128 + wn*64;
  int lr = lane & 15;
  int kg = lane >> 4;
  f32x4 acc[2][4];
  #pragma unroll
  for (int i = 0; i < 2; i++)
    #pragma unroll
    for (int j = 0; j < 4; j++) acc[i][j] = (f32x4){0.f,0.f,0.f,0.f};

  const f16* Ab = A  + (size_t)(rowbase >> 4)*4096 + kg*128 + lr*8;
  const f16* Bb = BT + (size_t)(colbase >> 4)*4096 + kg*128 + lr*8;

  f16x8 a0,a1,b0,b1,b2,b3;     // set X
  f16x8 c0,c1,d0,d1,d2,d3;     // set Y

#define LDX(K0) \
  a0 = *(const f16x8*)(Ab + 0*4096 + (K0)*16); a1 = *(const f16x8*)(Ab + 1*4096 + (K0)*16); \
  b0 = *(const f16x8*)(Bb + 0*4096 + (K0)*16); b1 = *(const f16x8*)(Bb + 1*4096 + (K0)*16); \
  b2 = *(const f16x8*)(Bb + 2*4096 + (K0)*16); b3 = *(const f16x8*)(Bb + 3*4096 + (K0)*16);
#define LDY(K0) \
  c0 = *(const f16x8*)(Ab + 0*4096 + (K0)*16); c1 = *(const f16x8*)(Ab + 1*4096 + (K0)*16); \
  d0 = *(const f16x8*)(Bb + 0*4096 + (K0)*16); d1 = *(const f16x8*)(Bb + 1*4096 + (K0)*16); \
  d2 = *(const f16x8*)(Bb + 2*4096 + (K0)*16); d3 = *(const f16x8*)(Bb + 3*4096 + (K0)*16);
#define MMX() \
  acc[0][0]=__builtin_amdgcn_mfma_f32_16x16x32_f16(b0,a0,acc[0][0],0,0,0); \
  acc[0][1]=__builtin_amdgcn_mfma_f32_16x16x32_f16(b1,a0,acc[0][1],0,0,0); \
  acc[0][2]=__builtin_amdgcn_mfma_f32_16x16x32_f16(b2,a0,acc[0][2],0,0,0); \
  acc[0][3]=__builtin_amdgcn_mfma_f32_16x16x32_f16(b3,a0,acc[0][3],0,0,0); \
  acc[1][0]=__builtin_amdgcn_mfma_f32_16x16x32_f16(b0,a1,acc[1][0],0,0,0); \
  acc[1][1]=__builtin_amdgcn_mfma_f32_16x16x32_f16(b1,a1,acc[1][1],0,0,0); \
  acc[1][2]=__builtin_amdgcn_mfma_f32_16x16x32_f16(b2,a1,acc[1][2],0,0,0); \
  acc[1][3]=__builtin_amdgcn_mfma_f32_16x16x32_f16(b3,a1,acc[1][3],0,0,0);
#define MMY() \
  acc[0][0]=__builtin_amdgcn_mfma_f32_16x16x32_f16(d0,c0,acc[0][0],0,0,0); \
  acc[0][1]=__builtin_amdgcn_mfma_f32_16x16x32_f16(d1,c0,acc[0][1],0,0,0); \
  acc[0][2]=__builtin_amdgcn_mfma_f32_16x16x32_f16(d2,c0,acc[0][2],0,0,0); \
  acc[0][3]=__builtin_amdgcn_mfma_f32_16x16x32_f16(d3,c0,acc[0][3],0,0,0); \
  acc[1][0]=__builtin_amdgcn_mfma_f32_16x16x32_f16(d0,c1,acc[1][0],0,0,0); \
  acc[1][1]=__builtin_amdgcn_mfma_f32_16x16x32_f16(d1,c1,acc[1][1],0,0,0); \
  acc[1][2]=__builtin_amdgcn_mfma_f32_16x16x32_f16(d2,c1,acc[1][2],0,0,0); \
  acc[1][3]=__builtin_amdgcn_mfma_f32_16x16x32_f16(d3,c1,acc[1][3],0,0,0);

  LDX(0)
  LDY(32)
  MMX()
  LDX(64)
  MMY()
  LDY(96)
  MMX()
  LDX(128)
  MMY()
  LDY(160)
  MMX()
  LDX(192)
  MMY()
  LDY(224)
  MMX()
  MMY()
#undef LDX
#undef LDY
#undef MMX
#undef MMY

  // D (swapped): lane holds C[row = rowbase+i*16+lr][col = colbase+j*16+kg*4+r], r=0..3
  #pragma unroll
  for (int j = 0; j < 4; j++) {
    int cb0 = colbase + j*16;
    if (cb0 >= 1040) continue;           // pad stripes: drop stores
    int colq = cb0 + kg*4;
    f32x4 bv = *(const f32x4*)(bias + colq);
    #pragma unroll
    for (int i = 0; i < 2; i++) {
      int row = rowbase + i*16 + lr;
      float v0 = acc[i][j][0]+bv[0], v1 = acc[i][j][1]+bv[1];
      float v2 = acc[i][j][2]+bv[2], v3 = acc[i][j][3]+bv[3];
      if (cb0 < 256) {                   // q -> qt8 int8, scale 32
        *(unsigned*)(qt8 + (size_t)row*256 + colq) = pack_i8x4(v0*32.f, v1*32.f, v2*32.f, v3*32.f);
      } else if (cb0 < 512) {            // k -> kvt int8, scale 32
        *(unsigned*)(kvt + (size_t)row*KVB + (colq-256)) = pack_i8x4(v0*32.f, v1*32.f, v2*32.f, v3*32.f);
      } else if (cb0 < 768) {            // v -> kvt fp8
        *(unsigned*)(kvt + (size_t)row*KVB + 256 + (colq-512)) = pack_fp8x4(v0, v1, v2, v3);
      } else if (cb0 < 1024) {           // skip -> gsk f16
        f16x4 st = { (f16)v0, (f16)v1, (f16)v2, (f16)v3 };
        *(f16x4*)(gsk + (size_t)row*GSS + (colq-768)) = st;
      } else {                           // qe/qb -> gsk f16 x SCQ
        f16x4 st = { (f16)(v0*SCQ), (f16)(v1*SCQ), (f16)(v2*SCQ), (f16)(v3*SCQ) };
        *(f16x4*)(gsk + (size_t)row*GSS + 256 + (colq-1024)) = st;
      }
    }
  }
}

// ---------------- attn phase 1: edge-parallel alpha + per-node stats ----------------
__global__ __launch_bounds__(256) void k_alpha(
    const unsigned char* __restrict__ qt8, const unsigned char* __restrict__ kvt,
    const f16* __restrict__ gsk, char* __restrict__ rec,
    const int* __restrict__ cnt, float* __restrict__ stats)
{
  int wid = threadIdx.x >> 6, lane = threadIdx.x & 63;
  int u = __builtin_amdgcn_readfirstlane(blockIdx.x*4 + wid);   // NN % 4 == 0
  int deg = cnt[u];
  const uint4* qp = (const uint4*)(qt8 + (size_t)u*256);
  uint4 q[16];
  #pragma unroll
  for (int c = 0; c < 16; c++) q[c] = qp[c];
  const f16* gb = gsk + (size_t)u*GSS;
  f16x8 qe8 = *(const f16x8*)(gb + 256);
  float qbv = (float)gb[264];
  size_t ub = (size_t)u*CAP;

  float ssum = 0.f;
  float ae[8];
  #pragma unroll
  for (int j = 0; j < 8; j++) ae[j] = 0.f;

  for (int i = lane; i < deg; i += 64) {
    char* rp = rec + (ub + i)*RECB;
    f16x8 ea = *(const f16x8*)rp;
    int sn = *(const int*)(rp + 16);
    const uint4* kp = (const uint4*)(kvt + (size_t)sn*KVB);
    int di = 0;
    #pragma unroll
    for (int c = 0; c < 16; c++) {
      uint4 kw = kp[c];
      di = sdot4(kw.x, q[c].x, di);
      di = sdot4(kw.y, q[c].y, di);
      di = sdot4(kw.z, q[c].z, di);
      di = sdot4(kw.w, q[c].w, di);
    }
    float edot = 0.f;
    edot = fdot2((h2){ea[0],ea[1]}, (h2){qe8[0],qe8[1]}, edot);
    edot = fdot2((h2){ea[2],ea[3]}, (h2){qe8[2],qe8[3]}, edot);
    edot = fdot2((h2){ea[4],ea[5]}, (h2){qe8[4],qe8[5]}, edot);
    edot = fdot2((h2){ea[6],ea[7]}, (h2){qe8[6],qe8[7]}, edot);
    float w = fast_exp2((float)di*ISCL + edot + qbv);
    *(float*)(rp + 20) = w;
    ssum += w;
    #pragma unroll
    for (int j = 0; j < 8; j++) ae[j] += w*(float)ea[j];
  }

  // butterfly reduce {ssum, ae[8]} across the wave
  #pragma unroll
  for (int o = 1; o < 64; o <<= 1) {
    ssum += __shfl_xor(ssum, o, 64);
    #pragma unroll
    for (int j = 0; j < 8; j++) ae[j] += __shfl_xor(ae[j], o, 64);
  }
  if (lane == 0) {
    float* sp = stats + (size_t)u*12;
    sp[0] = ssum;
    *(f32x4*)(sp + 4) = (f32x4){ae[0], ae[1], ae[2], ae[3]};
    *(f32x4*)(sp + 8) = (f32x4){ae[4], ae[5], ae[6], ae[7]};
  }
}

// ---------------- attn phase 2: group-form v-stream (4 edges in flight/wave, no ea work) ----------------
__global__ __launch_bounds__(256) void k_attn2(
    const unsigned char* __restrict__ kvt, const f16* __restrict__ gsk,
    const char* __restrict__ rec,
    const float* __restrict__ WeL, const float* __restrict__ beL,
    const int* __restrict__ cnt, const float* __restrict__ stats,
    f16* __restrict__ hout)
{
  int wid  = threadIdx.x >> 6;
  int lane = threadIdx.x & 63;
  int grp  = lane >> 4;         // edge group 0..3
  int gl   = lane & 15;         // lane in group: owns v bytes gl*16..gl*16+15
  int u = blockIdx.x*4 + wid;   // NN % 4 == 0
  int deg = cnt[u];
  size_t ub = (size_t)u*CAP;

  float av[16];
  #pragma unroll
  for (int j = 0; j < 16; j++) av[j] = 0.f;

  #pragma unroll 2
  for (int i = grp; i < deg; i += 4) {
    const char* rp = rec + (ub + i)*RECB;
    int2 sw = *(const int2*)(rp + 16);       // {src, w-bits} broadcast within group
    float w = __int_as_float(sw.y);
    uint4 vw = *(const uint4*)(kvt + (size_t)sw.x*KVB + 256 + gl*16);
    f32x2 p;
    p = unpack_fp8x2<false>(vw.x); av[0]  += w*p[0]; av[1]  += w*p[1];
    p = unpack_fp8x2<true >(vw.x); av[2]  += w*p[0]; av[3]  += w*p[1];
    p = unpack_fp8x2<false>(vw.y); av[4]  += w*p[0]; av[5]  += w*p[1];
    p = unpack_fp8x2<true >(vw.y); av[6]  += w*p[0]; av[7]  += w*p[1];
    p = unpack_fp8x2<false>(vw.z); av[8]  += w*p[0]; av[9]  += w*p[1];
    p = unpack_fp8x2<true >(vw.z); av[10] += w*p[0]; av[11] += w*p[1];
    p = unpack_fp8x2<false>(vw.w); av[12] += w*p[0]; av[13] += w*p[1];
    p = unpack_fp8x2<true >(vw.w); av[14] += w*p[0]; av[15] += w*p[1];
  }

  // cross-group reduce (groups at lane bits 4,5)
  #pragma unroll
  for (int j = 0; j < 16; j++) {
    av[j] += __shfl_xor(av[j], 16, 64);
    av[j] += __shfl_xor(av[j], 32, 64);
  }

  const float* sp = stats + (size_t)u*12;
  float ssum = sp[0];
  f32x4 aeA = *(const f32x4*)(sp + 4);
  f32x4 aeB = *(const f32x4*)(sp + 8);
  float inv = 1.f/(ssum + 1e-16f);

  // lane finalizes cols cb = gl*16 + grp*4 .. +3
  int cb = gl*16 + grp*4;
  f16x4 sk = *(const f16x4*)(gsk + (size_t)u*GSS + cb);
  f16 res[4];
  #pragma unroll
  for (int t = 0; t < 4; t++) {
    int c = cb + t;
    float o = av[grp*4+t];
    o += aeA[0]*WeL[0*256+c] + aeA[1]*WeL[1*256+c] + aeA[2]*WeL[2*256+c] + aeA[3]*WeL[3*256+c];
    o += aeB[0]*WeL[4*256+c] + aeB[1]*WeL[5*256+c] + aeB[2]*WeL[6*256+c] + aeB[3]*WeL[7*256+c];
    o += ssum*beL[c];
    o = o*inv + (float)sk[t];
    res[t] = (f16)fmaxf(o, 0.f);
  }
  f16x4 outp = { res[0], res[1], res[2], res[3] };
  *(f16x4*)(hout + TIDX(u, cb)) = outp;
}

// ---------------- decoder: out[n][18] = h @ W_dec + b_dec (h tiled; f32x4 LDS math) ----------------
__global__ __launch_bounds__(256) void k_decoder(
    const f16* __restrict__ h, const float* __restrict__ Wd,
    const float* __restrict__ bd, float* __restrict__ out)
{
  int n0 = blockIdx.x*32;     // NN % 32 == 0: no guards
  __shared__ float hs[32*256];
  int tid = threadIdx.x;
  for (int j = tid; j < 32*32; j += 256) {
    int node = j >> 5, c8 = (j & 31)*8;
    f16x8 v = *(const f16x8*)(h + TIDX(n0 + node, c8));
    float* dst = &hs[node*256 + c8];
    #pragma unroll
    for (int e = 0; e < 8; e++) dst[e] = (float)v[e];
  }
  __syncthreads();
  for (int o = tid; o < 32*18; o += 256) {
    int ln = o/18, col = o - ln*18;
    int node = n0 + ln;
    float acc = bd[col];
    const float* hr = &hs[ln*256];
    #pragma unroll 4
    for (int k4 = 0; k4 < 64; k4++) {
      f32x4 hv = *(const f32x4*)(hr + k4*4);
      acc += hv[0]*Wd[(k4*4+0)*18+col] + hv[1]*Wd[(k4*4+1)*18+col]
           + hv[2]*Wd[(k4*4+2)*18+col] + hv[3]*Wd[(k4*4+3)*18+col];
    }
    out[(size_t)node*18 + col] = acc;
  }
}

// ---------------- launch ----------------
extern "C" void kernel_launch(void* const* d_in, const int* in_sizes, int n_in,
                              void* d_out, int out_size, void* d_ws, size_t ws_size,
                              hipStream_t stream)
{
  const float* x     = (const float*)d_in[0];
  const int*   ei    = (const int*)  d_in[1];
  const float* eattr = (const float*)d_in[2];
  const float* t     = (const float*)d_in[3];
  const float* s     = (const float*)d_in[4];
  const float* W_emb = (const float*)d_in[5];
  const float* b_emb = (const float*)d_in[6];
  const float* W_t   = (const float*)d_in[7];
  const float* b_t   = (const float*)d_in[8];
  const float* W_s   = (const float*)d_in[9];
  const float* b_s   = (const float*)d_in[10];
  const float* W_f   = (const float*)d_in[11];
  const float* b_f   = (const float*)d_in[12];
  const float* ln_g  = (const float*)d_in[13];
  const float* ln_b  = (const float*)d_in[14];
  const float* Wq    = (const float*)d_in[15];
  const float* bq    = (const float*)d_in[16];
  const float* Wk    = (const float*)d_in[17];
  const float* bk    = (const float*)d_in[18];
  const float* Wv    = (const float*)d_in[19];
  const float* bv    = (const float*)d_in[20];
  const float* We    = (const float*)d_in[21];
  const float* be    = (const float*)d_in[22];
  const float* Wsk   = (const float*)d_in[23];
  const float* bsk   = (const float*)d_in[24];
  const float* W_dec = (const float*)d_in[25];
  const float* b_dec = (const float*)d_in[26];

  float* wsf = (float*)d_ws;
  size_t off = 0;
  float* bc    = wsf + off; off += 256;
  float* b_all = wsf + off; off += (size_t)5*NOUT;
  f16*   Wch   = (f16*)(wsf + off); off += (size_t)46*256/2;
  f16*   WT    = (f16*)(wsf + off); off += (size_t)5*294912/2;
  unsigned char* qt8 = (unsigned char*)(wsf + off); off += (size_t)NPAD*256/4;
  unsigned char* kvt = (unsigned char*)(wsf + off); off += (size_t)NPAD*KVB/4;
  f16*   gsk   = (f16*)(wsf + off); off += (size_t)NPAD*GSS/2;
  f16*   hA    = (f16*)(wsf + off); off += (size_t)NPAD*256/2;
  f16*   hB    = (f16*)(wsf + off); off += (size_t)NPAD*256/2;
  char*  rec   = (char*)(wsf + off); off += (size_t)NN*CAP*RECB/4;
  float* stats = wsf + off; off += (size_t)NN*12;
  int*   cnt   = (int*)(wsf + off); off += NN;

  (void)hipMemsetAsync(cnt, 0, NN*sizeof(int), stream);
  k_prep_all<<<419, 256, 0, stream>>>(W_emb, W_t, W_s, W_f, b_emb, b_t, b_s, b_f,
                                      Wq, Wk, Wv, Wsk, We, be, bq, bk, bv, bsk,
                                      Wch, bc, WT, b_all, hA, hB);
  k_scatter <<<(NE+255)/256, 256, 0, stream>>>(ei, eattr, cnt, rec);

  k_encoder <<<NN/16, 256, 0, stream>>>(x, t, s, Wch, bc, ln_g, ln_b, hA);

  f16* hin = hA;
  f16* hot = hB;
  for (int L = 0; L < 5; L++) {
    k_gemm<<<(NPAD/128)*9, 512, 0, stream>>>(hin, WT + (size_t)L*294912,
                                             b_all + (size_t)L*NOUT, qt8, kvt, gsk);
    k_alpha<<<NN/4, 256, 0, stream>>>(qt8, kvt, gsk, rec, cnt, stats);
    k_attn2<<<NN/4, 256, 0, stream>>>(kvt, gsk, rec, We + (size_t)L*2048,
                                      be + (size_t)L*256, cnt, stats, hot);
    f16* tmp = hin; hin = hot; hot = tmp;
  }
  k_decoder<<<NN/32, 256, 0, stream>>>(hin, W_dec, b_dec, (float*)d_out);
}

// Round 18
// 574.845 us; speedup vs baseline: 1.0645x; 1.0645x over previous
//
#include <hip/hip_runtime.h>
#include <hip/hip_fp8.h>
#include <math.h>

#define NN 20000
#define NPAD 20096          // 157*128 padded rows
#define NE 640000
#define NOUT 1152           // GEMM cols: Q(256)|K(256)|V(256)|SKIP(256)|qe(8)|qb(1)|pad
#define GSS 272             // gsk row stride f16: skip[0..255] qe[256..263] qb[264] pad
#define KVB 512             // kvt row bytes: k i8[256] | v fp8[256]
#define CAP 80              // bucket capacity per node (validated R8..R17)
#define RECB 32             // edge record: ea f16x8 @0 | src i32 @16 | w f32 @20 | pad
#define SCQ 0.09016994f     // (1/sqrt(256)) * log2(e)
#define ISCL 8.8057e-5f     // SCQ / 1024  (int8 q,k both at scale 32)
#define NSCB ((NE+255)/256) // scatter blocks: 2500
// fragment-tiled index: [rowtile16][kblk8][r16][k8]
#define TIDX(r,k) ((((r)>>4)*4096) + (((k)>>3)*128) + (((r)&15)*8) + ((k)&7))

typedef _Float16 f16;
typedef f16 f16x8 __attribute__((ext_vector_type(8)));
typedef f16 f16x4 __attribute__((ext_vector_type(4)));
typedef f16 h2    __attribute__((ext_vector_type(2)));
typedef float f32x4 __attribute__((ext_vector_type(4)));
typedef float f32x2 __attribute__((ext_vector_type(2)));

static __device__ __forceinline__ float fdot2(h2 a, h2 b, float c) {
#if __has_builtin(__builtin_amdgcn_fdot2)
  return __builtin_amdgcn_fdot2(a, b, c, false);
#else
  return c + (float)a[0]*(float)b[0] + (float)a[1]*(float)b[1];
#endif
}

static __device__ __forceinline__ float fast_exp2(float x) {
#if __has_builtin(__builtin_amdgcn_exp2f)
  return __builtin_amdgcn_exp2f(x);
#else
  return exp2f(x);
#endif
}

static __device__ __forceinline__ int sdot4(unsigned a, unsigned b, int c) {
#if __has_builtin(__builtin_amdgcn_sdot4)
  return __builtin_amdgcn_sdot4((int)a, (int)b, c, false);
#else
  int r = c;
  #pragma unroll
  for (int i = 0; i < 4; i++) {
    int ai = ((int)((a >> (8*i)) & 255) ^ 128) - 128;
    int bi = ((int)((b >> (8*i)) & 255) ^ 128) - 128;
    r += ai*bi;
  }
  return r;
#endif
}

static __device__ __forceinline__ unsigned pack_i8x4(float a, float b, float c, float d) {
  int i0 = (int)rintf(a), i1 = (int)rintf(b), i2 = (int)rintf(c), i3 = (int)rintf(d);
  i0 = max(-127, min(127, i0)); i1 = max(-127, min(127, i1));
  i2 = max(-127, min(127, i2)); i3 = max(-127, min(127, i3));
  return (unsigned)(i0 & 255) | ((unsigned)(i1 & 255) << 8)
       | ((unsigned)(i2 & 255) << 16) | ((unsigned)(i3 & 255) << 24);
}

static __device__ __forceinline__ unsigned pack_fp8x4(float a, float b, float c, float d) {
#if __has_builtin(__builtin_amdgcn_cvt_pk_fp8_f32)
  int r = __builtin_amdgcn_cvt_pk_fp8_f32(a, b, 0, false);
  r = __builtin_amdgcn_cvt_pk_fp8_f32(c, d, r, true);
  return (unsigned)r;
#else
  __hip_fp8_e4m3 w(a), x2(b), y(c), z(d);
  return (unsigned)w.__x | ((unsigned)x2.__x<<8) | ((unsigned)y.__x<<16) | ((unsigned)z.__x<<24);
#endif
}

template<bool HI>
static __device__ __forceinline__ f32x2 unpack_fp8x2(unsigned v) {
#if __has_builtin(__builtin_amdgcn_cvt_pk_f32_fp8)
  return __builtin_amdgcn_cvt_pk_f32_fp8((int)v, HI);
#else
  unsigned s = HI ? (v >> 16) : (v & 0xffff);
  __hip_fp8_e4m3 a, b; a.__x = (unsigned char)(s & 0xff); b.__x = (unsigned char)(s >> 8);
  return (f32x2){ (float)a, (float)b };
#endif
}

// ---------------- merged setup: weight prep + pad-zero + edge scatter (concurrent ranges) ----------------
// blocks 0..46: Wcomb | 47..366: tr | 367..411: extra | 412..416: bt | 417/418: h pads
// blocks 419..419+NSCB-1: bucketized edge scatter (independent of all prep outputs)
__global__ __launch_bounds__(256) void k_prep_all(
    const float* __restrict__ W_emb, const float* __restrict__ W_t,
    const float* __restrict__ W_s,   const float* __restrict__ W_f,
    const float* __restrict__ b_emb, const float* __restrict__ b_t,
    const float* __restrict__ b_s,   const float* __restrict__ b_f,
    const float* __restrict__ Wq, const float* __restrict__ Wk,
    const float* __restrict__ Wv, const float* __restrict__ Wsk,
    const float* __restrict__ We, const float* __restrict__ be,
    const float* __restrict__ bq, const float* __restrict__ bk,
    const float* __restrict__ bv, const float* __restrict__ bsk,
    const int* __restrict__ ei, const float* __restrict__ eattr,
    int* cnt, char* __restrict__ rec,
    f16* __restrict__ Wch, float* __restrict__ bc,
    f16* __restrict__ WT, float* __restrict__ b_all,
    f16* __restrict__ hA, f16* __restrict__ hB)
{
  __shared__ float smem[64*65];
  int b = blockIdx.x;
  int tid = threadIdx.x;

  if (b >= 419) {                      // ---- edge scatter (concurrent with prep) ----
    int e = (b - 419)*256 + tid;
    if (e < NE) {
      int d = ei[NE + e];
      int pos = atomicAdd(&cnt[d], 1);
      char* rp = rec + (size_t)(d*CAP + pos)*RECB;
      f32x4 a0 = *(const f32x4*)(eattr + (size_t)e*8);
      f32x4 a1 = *(const f32x4*)(eattr + (size_t)e*8 + 4);
      f16x8 ea = { (f16)a0[0],(f16)a0[1],(f16)a0[2],(f16)a0[3],
                   (f16)a1[0],(f16)a1[1],(f16)a1[2],(f16)a1[3] };
      *(f16x8*)rp = ea;
      *(int*)(rp + 16) = ei[e];
    }
    return;
  }

  if (b < 47) {                        // ---- Wcomb ----
    int r = b, c = tid;
    if (r < 36) {
      float a = 0.f;
      for (int m = 0; m < 256; m++) a += W_emb[r*256+m] * W_f[m*256+c];
      Wch[r*256+c] = (f16)a;
    } else if (r < 40) {
      int rr = r - 36; float a = 0.f;
      for (int m = 0; m < 256; m++) a += W_t[rr*256+m] * W_f[(256+m)*256+c];
      Wch[r*256+c] = (f16)a;
    } else if (r < 46) {
      int rr = r - 40; float a = 0.f;
      for (int m = 0; m < 256; m++) a += W_s[rr*256+m] * W_f[(512+m)*256+c];
      Wch[r*256+c] = (f16)a;
    } else {
      float a = b_f[c];
      for (int m = 0; m < 256; m++) a += b_emb[m]*W_f[m*256+c];
      for (int m = 0; m < 256; m++) a += b_t[m]*W_f[(256+m)*256+c];
      for (int m = 0; m < 256; m++) a += b_s[m]*W_f[(512+m)*256+c];
      bc[c] = a;
    }
  } else if (b < 367) {                // ---- tr: W[k][n] f32 -> WT tiled f16 ----
    float (*lds)[65] = (float(*)[65])smem;
    int bb = b - 47;
    int nt = bb & 3, kt = (bb >> 2) & 3, mat = (bb >> 4) & 3, L = bb >> 6;
    const float* src = (mat == 0 ? Wq : mat == 1 ? Wk : mat == 2 ? Wv : Wsk) + (size_t)L*65536;
    int k0 = kt*64, n0 = nt*64;
    int c = tid & 63, r4 = tid >> 6;
    #pragma unroll
    for (int rr = 0; rr < 16; rr++) {
      int row = rr*4 + r4;
      lds[row][c] = src[(size_t)(k0 + row)*256 + n0 + c];
    }
    __syncthreads();
    f16* dst = WT + (size_t)L*294912;
    int nl = tid & 63, kb2 = tid >> 6;
    int ng = mat*256 + n0 + nl;
    #pragma unroll
    for (int half = 0; half < 2; half++) {
      int kb = kb2 + half*4;
      f16x8 v;
      #pragma unroll
      for (int e = 0; e < 8; e++) v[e] = (f16)lds[kb*8 + e][nl];
      *(f16x8*)(dst + TIDX(ng, k0 + kb*8)) = v;
    }
  } else if (b < 412) {                // ---- extra: qe/qb cols of WT ----
    float* vec = smem;
    int bb = b - 367;
    int L = bb / 9;
    int t = bb % 9;
    vec[tid] = (t < 8) ? We[(size_t)L*2048 + t*256 + tid] : be[(size_t)L*256 + tid];
    __syncthreads();
    int wave = tid >> 6, lane = tid & 63;
    for (int k = wave; k < 256; k += 4) {
      f32x4 wq = *(const f32x4*)(Wq + (size_t)L*65536 + (size_t)k*256 + lane*4);
      f32x4 vv = *(const f32x4*)(vec + lane*4);
      float d = wq[0]*vv[0] + wq[1]*vv[1] + wq[2]*vv[2] + wq[3]*vv[3];
      #pragma unroll
      for (int o = 32; o; o >>= 1) d += __shfl_xor(d, o, 64);
      if (lane == 0) WT[(size_t)L*294912 + TIDX(1024 + t, k)] = (f16)d;
    }
  } else if (b < 417) {                // ---- bt: fused bias ----
    int L = b - 412;
    for (int c = tid; c < NOUT; c += 256) {
      float v;
      if (c < 256)       v = bq [L*256+c];
      else if (c < 512)  v = bk [L*256+(c-256)];
      else if (c < 768)  v = bv [L*256+(c-512)];
      else if (c < 1024) v = bsk[L*256+(c-768)];
      else if (c < 1032) {
        int t = c-1024; float a = 0.f;
        for (int m = 0; m < 256; m++) a += bq[L*256+m]*We[(size_t)L*2048 + t*256 + m];
        v = a;
      } else if (c == 1032) {
        float a = 0.f;
        for (int m = 0; m < 256; m++) a += bq[L*256+m]*be[L*256+m];
        v = a;
      } else v = 0.f;
      b_all[(size_t)L*NOUT + c] = v;
    }
  } else {                             // ---- zero pad rows [NN, NPAD) of hA/hB ----
    f16* p = (b == 417 ? hA : hB) + (size_t)NN*256;   // TIDX tail is contiguous
    f16x8 z = {};
    for (int i = tid; i < (NPAD-NN)*256/8; i += 256)
      *(f16x8*)(p + (size_t)i*8) = z;
  }
}

// ---------------- encoder: 16 nodes/block, Wc f16 in LDS, per-node 16-lane shfl LN ----------------
__global__ __launch_bounds__(256) void k_encoder(
    const float* __restrict__ x, const float* __restrict__ t, const float* __restrict__ s,
    const f16* __restrict__ Wch, const float* __restrict__ bc,
    const float* __restrict__ lng, const float* __restrict__ lnb,
    f16* __restrict__ h)
{
  __shared__ f16 Wcs[46*256];
  __shared__ float xin[16][48];
  __shared__ float bcs[256], lgs[256], lbs[256];
  int tid = threadIdx.x;
  int u0 = blockIdx.x * 16;
  for (int i = tid; i < 46*128; i += 256)
    ((unsigned int*)Wcs)[i] = ((const unsigned int*)Wch)[i];
  bcs[tid] = bc[tid]; lgs[tid] = lng[tid]; lbs[tid] = lnb[tid];
  for (int i = tid; i < 576; i += 256) xin[i/36][i%36] = x[(size_t)u0*36 + i];
  if (tid < 64) xin[tid>>2][36 + (tid&3)] = t[(size_t)u0*4 + tid];
  if (tid < 96) xin[tid/6][40 + tid%6] = s[(size_t)u0*6 + tid];
  __syncthreads();
  int node = tid >> 4, cg = tid & 15;
  int u = u0 + node;
  float acc[16];
  #pragma unroll
  for (int j = 0; j < 16; j++) acc[j] = bcs[cg*16+j];
  for (int r = 0; r < 46; r++) {
    float xv = xin[node][r];
    const h2* wr = (const h2*)(Wcs + r*256 + cg*16);
    #pragma unroll
    for (int j2 = 0; j2 < 8; j2++) {
      h2 w2 = wr[j2];
      acc[j2*2]   += xv * (float)w2[0];
      acc[j2*2+1] += xv * (float)w2[1];
    }
  }
  float sm = 0.f, sq = 0.f;
  #pragma unroll
  for (int j = 0; j < 16; j++) { sm += acc[j]; sq += acc[j]*acc[j]; }
  #pragma unroll
  for (int o = 1; o < 16; o <<= 1) { sm += __shfl_xor(sm, o, 64); sq += __shfl_xor(sq, o, 64); }
  float mu  = sm * (1.f/256.f);
  float var = sq * (1.f/256.f) - mu*mu;
  float rin = rsqrtf(var + 1e-5f);
  f16x8 o0, o1;
  #pragma unroll
  for (int j = 0; j < 8; j++) {
    int c = cg*16 + j;
    float v = (acc[j]-mu)*rin*lgs[c] + lbs[c];
    o0[j] = (f16)fmaxf(v, 0.f);
  }
  #pragma unroll
  for (int j = 0; j < 8; j++) {
    int c = cg*16 + 8 + j;
    float v = (acc[8+j]-mu)*rin*lgs[c] + lbs[c];
    o1[j] = (f16)fmaxf(v, 0.f);
  }
  *(f16x8*)(h + TIDX(u, cg*16))   = o0;
  *(f16x8*)(h + TIDX(u, cg*16+8)) = o1;
}

// ---------------- MFMA GEMM: XCD-swizzled, 4 waves, explicit 1-deep register prefetch (R16) ----------------
__global__ __launch_bounds__(256) void k_gemm(
    const f16* __restrict__ A, const f16* __restrict__ BT,
    const float* __restrict__ bias,
    unsigned char* __restrict__ qt8, unsigned char* __restrict__ kvt,
    f16* __restrict__ gsk)
{
  const int NWG = (NPAD/128)*9;           // 1413
  const int Q = NWG >> 3, R = NWG & 7;    // 176, 5
  int bid = blockIdx.x;
  int xcd = bid & 7, jj = bid >> 3;
  int wg = (xcd < R ? xcd*(Q+1) : R*(Q+1) + (xcd-R)*Q) + jj;
  int bmt = wg / 9, bnt = wg - bmt*9;

  int tid = threadIdx.x;
  int wave = tid >> 6, lane = tid & 63;
  int wm = wave >> 1, wn = wave & 1;
  int bm = bmt*128 + wm*64;
  int bn = bnt*128 + wn*64;
  int lr = lane & 15;
  int kg = lane >> 4;
  f32x4 acc[4][4];
  #pragma unroll
  for (int i = 0; i < 4; i++)
    #pragma unroll
    for (int j = 0; j < 4; j++) acc[i][j] = (f32x4){0.f,0.f,0.f,0.f};

  const f16* Ab = A  + (size_t)(bm >> 4)*4096 + kg*128 + lr*8;
  const f16* Bb = BT + (size_t)(bn >> 4)*4096 + kg*128 + lr*8;

  f16x8 a0,a1,a2,a3,b0,b1,b2,b3;     // set X
  f16x8 c0,c1,c2,c3,d0,d1,d2,d3;     // set Y

#define LDX(K0) \
  a0 = *(const f16x8*)(Ab + 0*4096 + (K0)*16); a1 = *(const f16x8*)(Ab + 1*4096 + (K0)*16); \
  a2 = *(const f16x8*)(Ab + 2*4096 + (K0)*16); a3 = *(const f16x8*)(Ab + 3*4096 + (K0)*16); \
  b0 = *(const f16x8*)(Bb + 0*4096 + (K0)*16); b1 = *(const f16x8*)(Bb + 1*4096 + (K0)*16); \
  b2 = *(const f16x8*)(Bb + 2*4096 + (K0)*16); b3 = *(const f16x8*)(Bb + 3*4096 + (K0)*16);
#define LDY(K0) \
  c0 = *(const f16x8*)(Ab + 0*4096 + (K0)*16); c1 = *(const f16x8*)(Ab + 1*4096 + (K0)*16); \
  c2 = *(const f16x8*)(Ab + 2*4096 + (K0)*16); c3 = *(const f16x8*)(Ab + 3*4096 + (K0)*16); \
  d0 = *(const f16x8*)(Bb + 0*4096 + (K0)*16); d1 = *(const f16x8*)(Bb + 1*4096 + (K0)*16); \
  d2 = *(const f16x8*)(Bb + 2*4096 + (K0)*16); d3 = *(const f16x8*)(Bb + 3*4096 + (K0)*16);
#define MMX() \
  acc[0][0]=__builtin_amdgcn_mfma_f32_16x16x32_f16(b0,a0,acc[0][0],0,0,0); \
  acc[0][1]=__builtin_amdgcn_mfma_f32_16x16x32_f16(b1,a0,acc[0][1],0,0,0); \
  acc[0][2]=__builtin_amdgcn_mfma_f32_16x16x32_f16(b2,a0,acc[0][2],0,0,0); \
  acc[0][3]=__builtin_amdgcn_mfma_f32_16x16x32_f16(b3,a0,acc[0][3],0,0,0); \
  acc[1][0]=__builtin_amdgcn_mfma_f32_16x16x32_f16(b0,a1,acc[1][0],0,0,0); \
  acc[1][1]=__builtin_amdgcn_mfma_f32_16x16x32_f16(b1,a1,acc[1][1],0,0,0); \
  acc[1][2]=__builtin_amdgcn_mfma_f32_16x16x32_f16(b2,a1,acc[1][2],0,0,0); \
  acc[1][3]=__builtin_amdgcn_mfma_f32_16x16x32_f16(b3,a1,acc[1][3],0,0,0); \
  acc[2][0]=__builtin_amdgcn_mfma_f32_16x16x32_f16(b0,a2,acc[2][0],0,0,0); \
  acc[2][1]=__builtin_amdgcn_mfma_f32_16x16x32_f16(b1,a2,acc[2][1],0,0,0); \
  acc[2][2]=__builtin_amdgcn_mfma_f32_16x16x32_f16(b2,a2,acc[2][2],0,0,0); \
  acc[2][3]=__builtin_amdgcn_mfma_f32_16x16x32_f16(b3,a2,acc[2][3],0,0,0); \
  acc[3][0]=__builtin_amdgcn_mfma_f32_16x16x32_f16(b0,a3,acc[3][0],0,0,0); \
  acc[3][1]=__builtin_amdgcn_mfma_f32_16x16x32_f16(b1,a3,acc[3][1],0,0,0); \
  acc[3][2]=__builtin_amdgcn_mfma_f32_16x16x32_f16(b2,a3,acc[3][2],0,0,0); \
  acc[3][3]=__builtin_amdgcn_mfma_f32_16x16x32_f16(b3,a3,acc[3][3],0,0,0);
#define MMY() \
  acc[0][0]=__builtin_amdgcn_mfma_f32_16x16x32_f16(d0,c0,acc[0][0],0,0,0); \
  acc[0][1]=__builtin_amdgcn_mfma_f32_16x16x32_f16(d1,c0,acc[0][1],0,0,0); \
  acc[0][2]=__builtin_amdgcn_mfma_f32_16x16x32_f16(d2,c0,acc[0][2],0,0,0); \
  acc[0][3]=__builtin_amdgcn_mfma_f32_16x16x32_f16(d3,c0,acc[0][3],0,0,0); \
  acc[1][0]=__builtin_amdgcn_mfma_f32_16x16x32_f16(d0,c1,acc[1][0],0,0,0); \
  acc[1][1]=__builtin_amdgcn_mfma_f32_16x16x32_f16(d1,c1,acc[1][1],0,0,0); \
  acc[1][2]=__builtin_amdgcn_mfma_f32_16x16x32_f16(d2,c1,acc[1][2],0,0,0); \
  acc[1][3]=__builtin_amdgcn_mfma_f32_16x16x32_f16(d3,c1,acc[1][3],0,0,0); \
  acc[2][0]=__builtin_amdgcn_mfma_f32_16x16x32_f16(d0,c2,acc[2][0],0,0,0); \
  acc[2][1]=__builtin_amdgcn_mfma_f32_16x16x32_f16(d1,c2,acc[2][1],0,0,0); \
  acc[2][2]=__builtin_amdgcn_mfma_f32_16x16x32_f16(d2,c2,acc[2][2],0,0,0); \
  acc[2][3]=__builtin_amdgcn_mfma_f32_16x16x32_f16(d3,c2,acc[2][3],0,0,0); \
  acc[3][0]=__builtin_amdgcn_mfma_f32_16x16x32_f16(d0,c3,acc[3][0],0,0,0); \
  acc[3][1]=__builtin_amdgcn_mfma_f32_16x16x32_f16(d1,c3,acc[3][1],0,0,0); \
  acc[3][2]=__builtin_amdgcn_mfma_f32_16x16x32_f16(d2,c3,acc[3][2],0,0,0); \
  acc[3][3]=__builtin_amdgcn_mfma_f32_16x16x32_f16(d3,c3,acc[3][3],0,0,0);

  LDX(0)
  LDY(32)
  MMX()
  LDX(64)
  MMY()
  LDY(96)
  MMX()
  LDX(128)
  MMY()
  LDY(160)
  MMX()
  LDX(192)
  MMY()
  LDY(224)
  MMX()
  MMY()
#undef LDX
#undef LDY
#undef MMX
#undef MMY

  // D (swapped): lane holds C[row = bm+i*16+lr][col = bn+j*16+kg*4+r], r=0..3
  #pragma unroll
  for (int j = 0; j < 4; j++) {
    int cb0 = bn + j*16;
    if (cb0 >= 1040) continue;           // pad stripes: drop stores
    int colq = cb0 + kg*4;
    f32x4 bv = *(const f32x4*)(bias + colq);
    #pragma unroll
    for (int i = 0; i < 4; i++) {
      int row = bm + i*16 + lr;
      float v0 = acc[i][j][0]+bv[0], v1 = acc[i][j][1]+bv[1];
      float v2 = acc[i][j][2]+bv[2], v3 = acc[i][j][3]+bv[3];
      if (cb0 < 256) {                   // q -> qt8 int8, scale 32
        *(unsigned*)(qt8 + (size_t)row*256 + colq) = pack_i8x4(v0*32.f, v1*32.f, v2*32.f, v3*32.f);
      } else if (cb0 < 512) {            // k -> kvt int8, scale 32
        *(unsigned*)(kvt + (size_t)row*KVB + (colq-256)) = pack_i8x4(v0*32.f, v1*32.f, v2*32.f, v3*32.f);
      } else if (cb0 < 768) {            // v -> kvt fp8
        *(unsigned*)(kvt + (size_t)row*KVB + 256 + (colq-512)) = pack_fp8x4(v0, v1, v2, v3);
      } else if (cb0 < 1024) {           // skip -> gsk f16
        f16x4 st = { (f16)v0, (f16)v1, (f16)v2, (f16)v3 };
        *(f16x4*)(gsk + (size_t)row*GSS + (colq-768)) = st;
      } else {                           // qe/qb -> gsk f16 x SCQ
        f16x4 st = { (f16)(v0*SCQ), (f16)(v1*SCQ), (f16)(v2*SCQ), (f16)(v3*SCQ) };
        *(f16x4*)(gsk + (size_t)row*GSS + 256 + (colq-1024)) = st;
      }
    }
  }
}

// ---------------- attn phase 1: edge-parallel alpha + per-node stats ----------------
__global__ __launch_bounds__(256) void k_alpha(
    const unsigned char* __restrict__ qt8, const unsigned char* __restrict__ kvt,
    const f16* __restrict__ gsk, char* __restrict__ rec,
    const int* __restrict__ cnt, float* __restrict__ stats)
{
  int wid = threadIdx.x >> 6, lane = threadIdx.x & 63;
  int u = __builtin_amdgcn_readfirstlane(blockIdx.x*4 + wid);   // NN % 4 == 0
  int deg = cnt[u];
  const uint4* qp = (const uint4*)(qt8 + (size_t)u*256);
  uint4 q[16];
  #pragma unroll
  for (int c = 0; c < 16; c++) q[c] = qp[c];
  const f16* gb = gsk + (size_t)u*GSS;
  f16x8 qe8 = *(const f16x8*)(gb + 256);
  float qbv = (float)gb[264];
  size_t ub = (size_t)u*CAP;

  float ssum = 0.f;
  float ae[8];
  #pragma unroll
  for (int j = 0; j < 8; j++) ae[j] = 0.f;

  for (int i = lane; i < deg; i += 64) {
    char* rp = rec + (ub + i)*RECB;
    f16x8 ea = *(const f16x8*)rp;
    int sn = *(const int*)(rp + 16);
    const uint4* kp = (const uint4*)(kvt + (size_t)sn*KVB);
    int di = 0;
    #pragma unroll
    for (int c = 0; c < 16; c++) {
      uint4 kw = kp[c];
      di = sdot4(kw.x, q[c].x, di);
      di = sdot4(kw.y, q[c].y, di);
      di = sdot4(kw.z, q[c].z, di);
      di = sdot4(kw.w, q[c].w, di);
    }
    float edot = 0.f;
    edot = fdot2((h2){ea[0],ea[1]}, (h2){qe8[0],qe8[1]}, edot);
    edot = fdot2((h2){ea[2],ea[3]}, (h2){qe8[2],qe8[3]}, edot);
    edot = fdot2((h2){ea[4],ea[5]}, (h2){qe8[4],qe8[5]}, edot);
    edot = fdot2((h2){ea[6],ea[7]}, (h2){qe8[6],qe8[7]}, edot);
    float w = fast_exp2((float)di*ISCL + edot + qbv);
    *(float*)(rp + 20) = w;
    ssum += w;
    #pragma unroll
    for (int j = 0; j < 8; j++) ae[j] += w*(float)ea[j];
  }

  // butterfly reduce {ssum, ae[8]} across the wave
  #pragma unroll
  for (int o = 1; o < 64; o <<= 1) {
    ssum += __shfl_xor(ssum, o, 64);
    #pragma unroll
    for (int j = 0; j < 8; j++) ae[j] += __shfl_xor(ae[j], o, 64);
  }
  if (lane == 0) {
    float* sp = stats + (size_t)u*12;
    sp[0] = ssum;
    *(f32x4*)(sp + 4) = (f32x4){ae[0], ae[1], ae[2], ae[3]};
    *(f32x4*)(sp + 8) = (f32x4){ae[4], ae[5], ae[6], ae[7]};
  }
}

// ---------------- attn phase 2: group-form v-stream (4 edges in flight/wave, no ea work) ----------------
__global__ __launch_bounds__(256) void k_attn2(
    const unsigned char* __restrict__ kvt, const f16* __restrict__ gsk,
    const char* __restrict__ rec,
    const float* __restrict__ WeL, const float* __restrict__ beL,
    const int* __restrict__ cnt, const float* __restrict__ stats,
    f16* __restrict__ hout)
{
  int wid  = threadIdx.x >> 6;
  int lane = threadIdx.x & 63;
  int grp  = lane >> 4;         // edge group 0..3
  int gl   = lane & 15;         // lane in group: owns v bytes gl*16..gl*16+15
  int u = blockIdx.x*4 + wid;   // NN % 4 == 0
  int deg = cnt[u];
  size_t ub = (size_t)u*CAP;

  float av[16];
  #pragma unroll
  for (int j = 0; j < 16; j++) av[j] = 0.f;

  #pragma unroll 2
  for (int i = grp; i < deg; i += 4) {
    const char* rp = rec + (ub + i)*RECB;
    int2 sw = *(const int2*)(rp + 16);       // {src, w-bits} broadcast within group
    float w = __int_as_float(sw.y);
    uint4 vw = *(const uint4*)(kvt + (size_t)sw.x*KVB + 256 + gl*16);
    f32x2 p;
    p = unpack_fp8x2<false>(vw.x); av[0]  += w*p[0]; av[1]  += w*p[1];
    p = unpack_fp8x2<true >(vw.x); av[2]  += w*p[0]; av[3]  += w*p[1];
    p = unpack_fp8x2<false>(vw.y); av[4]  += w*p[0]; av[5]  += w*p[1];
    p = unpack_fp8x2<true >(vw.y); av[6]  += w*p[0]; av[7]  += w*p[1];
    p = unpack_fp8x2<false>(vw.z); av[8]  += w*p[0]; av[9]  += w*p[1];
    p = unpack_fp8x2<true >(vw.z); av[10] += w*p[0]; av[11] += w*p[1];
    p = unpack_fp8x2<false>(vw.w); av[12] += w*p[0]; av[13] += w*p[1];
    p = unpack_fp8x2<true >(vw.w); av[14] += w*p[0]; av[15] += w*p[1];
  }

  // cross-group reduce (groups at lane bits 4,5)
  #pragma unroll
  for (int j = 0; j < 16; j++) {
    av[j] += __shfl_xor(av[j], 16, 64);
    av[j] += __shfl_xor(av[j], 32, 64);
  }

  const float* sp = stats + (size_t)u*12;
  float ssum = sp[0];
  f32x4 aeA = *(const f32x4*)(sp + 4);
  f32x4 aeB = *(const f32x4*)(sp + 8);
  float inv = 1.f/(ssum + 1e-16f);

  // lane finalizes cols cb = gl*16 + grp*4 .. +3
  int cb = gl*16 + grp*4;
  f16x4 sk = *(const f16x4*)(gsk + (size_t)u*GSS + cb);
  f16 res[4];
  #pragma unroll
  for (int t = 0; t < 4; t++) {
    int c = cb + t;
    float o = av[grp*4+t];
    o += aeA[0]*WeL[0*256+c] + aeA[1]*WeL[1*256+c] + aeA[2]*WeL[2*256+c] + aeA[3]*WeL[3*256+c];
    o += aeB[0]*WeL[4*256+c] + aeB[1]*WeL[5*256+c] + aeB[2]*WeL[6*256+c] + aeB[3]*WeL[7*256+c];
    o += ssum*beL[c];
    o = o*inv + (float)sk[t];
    res[t] = (f16)fmaxf(o, 0.f);
  }
  f16x4 outp = { res[0], res[1], res[2], res[3] };
  *(f16x4*)(hout + TIDX(u, cb)) = outp;
}

// ---------------- decoder: out[n][18] = h @ W_dec + b_dec (h tiled; f32x4 LDS math) ----------------
__global__ __launch_bounds__(256) void k_decoder(
    const f16* __restrict__ h, const float* __restrict__ Wd,
    const float* __restrict__ bd, float* __restrict__ out)
{
  int n0 = blockIdx.x*32;     // NN % 32 == 0: no guards
  __shared__ float hs[32*256];
  int tid = threadIdx.x;
  for (int j = tid; j < 32*32; j += 256) {
    int node = j >> 5, c8 = (j & 31)*8;
    f16x8 v = *(const f16x8*)(h + TIDX(n0 + node, c8));
    float* dst = &hs[node*256 + c8];
    #pragma unroll
    for (int e = 0; e < 8; e++) dst[e] = (float)v[e];
  }
  __syncthreads();
  for (int o = tid; o < 32*18; o += 256) {
    int ln = o/18, col = o - ln*18;
    int node = n0 + ln;
    float acc = bd[col];
    const float* hr = &hs[ln*256];
    #pragma unroll 4
    for (int k4 = 0; k4 < 64; k4++) {
      f32x4 hv = *(const f32x4*)(hr + k4*4);
      acc += hv[0]*Wd[(k4*4+0)*18+col] + hv[1]*Wd[(k4*4+1)*18+col]
           + hv[2]*Wd[(k4*4+2)*18+col] + hv[3]*Wd[(k4*4+3)*18+col];
    }
    out[(size_t)node*18 + col] = acc;
  }
}

// ---------------- launch ----------------
extern "C" void kernel_launch(void* const* d_in, const int* in_sizes, int n_in,
                              void* d_out, int out_size, void* d_ws, size_t ws_size,
                              hipStream_t stream)
{
  const float* x     = (const float*)d_in[0];
  const int*   ei    = (const int*)  d_in[1];
  const float* eattr = (const float*)d_in[2];
  const float* t     = (const float*)d_in[3];
  const float* s     = (const float*)d_in[4];
  const float* W_emb = (const float*)d_in[5];
  const float* b_emb = (const float*)d_in[6];
  const float* W_t   = (const float*)d_in[7];
  const float* b_t   = (const float*)d_in[8];
  const float* W_s   = (const float*)d_in[9];
  const float* b_s   = (const float*)d_in[10];
  const float* W_f   = (const float*)d_in[11];
  const float* b_f   = (const float*)d_in[12];
  const float* ln_g  = (const float*)d_in[13];
  const float* ln_b  = (const float*)d_in[14];
  const float* Wq    = (const float*)d_in[15];
  const float* bq    = (const float*)d_in[16];
  const float* Wk    = (const float*)d_in[17];
  const float* bk    = (const float*)d_in[18];
  const float* Wv    = (const float*)d_in[19];
  const float* bv    = (const float*)d_in[20];
  const float* We    = (const float*)d_in[21];
  const float* be    = (const float*)d_in[22];
  const float* Wsk   = (const float*)d_in[23];
  const float* bsk   = (const float*)d_in[24];
  const float* W_dec = (const float*)d_in[25];
  const float* b_dec = (const float*)d_in[26];

  float* wsf = (float*)d_ws;
  size_t off = 0;
  float* bc    = wsf + off; off += 256;
  float* b_all = wsf + off; off += (size_t)5*NOUT;
  f16*   Wch   = (f16*)(wsf + off); off += (size_t)46*256/2;
  f16*   WT    = (f16*)(wsf + off); off += (size_t)5*294912/2;
  unsigned char* qt8 = (unsigned char*)(wsf + off); off += (size_t)NPAD*256/4;
  unsigned char* kvt = (unsigned char*)(wsf + off); off += (size_t)NPAD*KVB/4;
  f16*   gsk   = (f16*)(wsf + off); off += (size_t)NPAD*GSS/2;
  f16*   hA    = (f16*)(wsf + off); off += (size_t)NPAD*256/2;
  f16*   hB    = (f16*)(wsf + off); off += (size_t)NPAD*256/2;
  char*  rec   = (char*)(wsf + off); off += (size_t)NN*CAP*RECB/4;
  float* stats = wsf + off; off += (size_t)NN*12;
  int*   cnt   = (int*)(wsf + off); off += NN;

  (void)hipMemsetAsync(cnt, 0, NN*sizeof(int), stream);
  k_prep_all<<<419 + NSCB, 256, 0, stream>>>(W_emb, W_t, W_s, W_f, b_emb, b_t, b_s, b_f,
                                             Wq, Wk, Wv, Wsk, We, be, bq, bk, bv, bsk,
                                             ei, eattr, cnt, rec,
                                             Wch, bc, WT, b_all, hA, hB);
  k_encoder <<<NN/16, 256, 0, stream>>>(x, t, s, Wch, bc, ln_g, ln_b, hA);

  f16* hin = hA;
  f16* hot = hB;
  for (int L = 0; L < 5; L++) {
    k_gemm<<<(NPAD/128)*9, 256, 0, stream>>>(hin, WT + (size_t)L*294912,
                                             b_all + (size_t)L*NOUT, qt8, kvt, gsk);
    k_alpha<<<NN/4, 256, 0, stream>>>(qt8, kvt, gsk, rec, cnt, stats);
    k_attn2<<<NN/4, 256, 0, stream>>>(kvt, gsk, rec, We + (size_t)L*2048,
                                      be + (size_t)L*256, cnt, stats, hot);
    f16* tmp = hin; hin = hot; hot = tmp;
  }
  k_decoder<<<NN/32, 256, 0, stream>>>(hin, W_dec, b_dec, (float*)d_out);
}